// Round 7
// baseline (316.506 us; speedup 1.0000x reference)
//
#include <hip/hip_runtime.h>
#include <hip/hip_bf16.h>
#include <math.h>

#define N_REFLNS 2000000
#define N_IMAGES 8192
#define N_RAC    1000000
#define MC       8
#define D_META   16
#define HIDDEN   32
#define LOG_2PI  1.8378770664093453f
#define LOG2E    1.44269504089f
#define LN2      0.69314718056f

// Workspace layout (bytes):
//   [0, 32768)          img_sum   (8192 f32)
//   [32768, 65536)      img_cnt   (8192 f32)
//   [65536, 65540)      kl_sum    (1 f32)
//   [65664, 65664+32e6) zT        (N_RAC x MC f32, transposed z for 32B gathers)

typedef __attribute__((ext_vector_type(8)))  short bf16x8;
typedef __attribute__((ext_vector_type(4)))  float f32x4;
typedef __attribute__((ext_vector_type(16))) float f32x16;

#define MFMA16(A, B, C) __builtin_amdgcn_mfma_f32_16x16x32_bf16(A, B, C, 0, 0, 0)
#define MFMA32(A, B, C) __builtin_amdgcn_mfma_f32_32x32x16_bf16(A, B, C, 0, 0, 0)

union B8 { bf16x8 v; unsigned u[4]; };

// Dekker split: hi = trunc-to-bf16, lo = trunc(x - hi). rel err ~2^-17.
__device__ __forceinline__ void split_hilo(const float* x, bf16x8& hi, bf16x8& lo) {
    B8 h, l;
    #pragma unroll
    for (int p = 0; p < 4; p++) {
        unsigned u0 = __float_as_uint(x[2 * p]);
        unsigned u1 = __float_as_uint(x[2 * p + 1]);
        unsigned hf0 = u0 & 0xFFFF0000u;
        unsigned hf1 = u1 & 0xFFFF0000u;
        h.u[p] = (u0 >> 16) | hf1;
        float d0 = x[2 * p]     - __uint_as_float(hf0);
        float d1 = x[2 * p + 1] - __uint_as_float(hf1);
        l.u[p] = (__float_as_uint(d0) >> 16) | (__float_as_uint(d1) & 0xFFFF0000u);
    }
    hi = h.v; lo = l.v;
}

// RNE pack via packed hw conversion (v_cvt_pk_bf16_f32 on gfx950).
__device__ __forceinline__ bf16x8 pack8_rne(float4 a0, float4 a1) {
    B8 r;
    __hip_bfloat162 t0 = __float22bfloat162_rn(make_float2(a0.x, a0.y));
    __hip_bfloat162 t1 = __float22bfloat162_rn(make_float2(a0.z, a0.w));
    __hip_bfloat162 t2 = __float22bfloat162_rn(make_float2(a1.x, a1.y));
    __hip_bfloat162 t3 = __float22bfloat162_rn(make_float2(a1.z, a1.w));
    r.u[0] = reinterpret_cast<unsigned&>(t0);
    r.u[1] = reinterpret_cast<unsigned&>(t1);
    r.u[2] = reinterpret_cast<unsigned&>(t2);
    r.u[3] = reinterpret_cast<unsigned&>(t3);
    return r.v;
}

// softplus via native v_exp/v_log (log2 domain)
__device__ __forceinline__ float softplus_fast(float x) {
    float t = __builtin_amdgcn_exp2f(-fabsf(x) * LOG2E);
    return fmaxf(x, 0.0f) + LN2 * __builtin_amdgcn_logf(1.0f + t);
}

// ---------------- Kernel A: zT + KL, 4 RAC entries per thread ----------------
__global__ __launch_bounds__(256) void k_z_kl(
    const float* __restrict__ q_loc,
    const float* __restrict__ q_log_scale,
    const float* __restrict__ eps,
    float* __restrict__ zT,          // may be null (fallback)
    float* __restrict__ kl_sum)
{
    int t = blockIdx.x * 256 + threadIdx.x;
    int r0 = t * 4;
    float kl = 0.0f;
    if (r0 < N_RAC) {
        float4 ql  = *(const float4*)(q_loc + r0);
        float4 qls = *(const float4*)(q_log_scale + r0);
        float4 qs;
        qs.x = __builtin_amdgcn_exp2f(qls.x * LOG2E);
        qs.y = __builtin_amdgcn_exp2f(qls.y * LOG2E);
        qs.z = __builtin_amdgcn_exp2f(qls.z * LOG2E);
        qs.w = __builtin_amdgcn_exp2f(qls.w * LOG2E);
        kl = 0.5f * (qs.x * qs.x + ql.x * ql.x - 1.0f) - qls.x
           + 0.5f * (qs.y * qs.y + ql.y * ql.y - 1.0f) - qls.y
           + 0.5f * (qs.z * qs.z + ql.z * ql.z - 1.0f) - qls.z
           + 0.5f * (qs.w * qs.w + ql.w * ql.w - 1.0f) - qls.w;
        if (zT) {
            float zr[4][MC];
            #pragma unroll
            for (int s = 0; s < MC; s++) {
                float4 e = *(const float4*)(eps + (size_t)s * N_RAC + r0);
                zr[0][s] = ql.x + qs.x * e.x;
                zr[1][s] = ql.y + qs.y * e.y;
                zr[2][s] = ql.z + qs.z * e.z;
                zr[3][s] = ql.w + qs.w * e.w;
            }
            #pragma unroll
            for (int r = 0; r < 4; r++) {
                float4* dst = (float4*)(zT + (size_t)(r0 + r) * MC);
                dst[0] = make_float4(zr[r][0], zr[r][1], zr[r][2], zr[r][3]);
                dst[1] = make_float4(zr[r][4], zr[r][5], zr[r][6], zr[r][7]);
            }
        }
    }
    __shared__ float sred[256];
    sred[threadIdx.x] = kl;
    __syncthreads();
    #pragma unroll
    for (int s = 128; s > 0; s >>= 1) {
        if (threadIdx.x < s) sred[threadIdx.x] += sred[threadIdx.x + s];
        __syncthreads();
    }
    if (threadIdx.x == 0) atomicAdd(kl_sum, sred[0]);
}

// ---------------- Kernel B: MFMA MLP + likelihood -----------------------------
// Block = 4 waves; each wave owns 64 reflections = 2 supertiles of 32 rows.
// LDS: ONE per-wave 32x36 f32 buffer, used as H during the MLP and REUSED as
// the logits staging buffer afterward (logits held in 16 VGPRs meanwhile).
// Same-wave DS ordering makes the reuse barrier-free. LDS/block = 18.4 KB ->
// up to 8 blocks/CU (was 5). launch_bounds(256,6) keeps VGPR <= 85.
template <bool HAS_Z>
__global__ __launch_bounds__(256, 6) void k_main(
    const float* __restrict__ metadata,
    const float* __restrict__ W1, const float* __restrict__ b1,
    const float* __restrict__ W2, const float* __restrict__ b2,
    const float* __restrict__ iobs, const float* __restrict__ sigiobs,
    const int* __restrict__ image_id, const int* __restrict__ miller_id,
    const float* __restrict__ zT,
    const float* __restrict__ q_loc, const float* __restrict__ q_log_scale,
    const float* __restrict__ eps,
    float* __restrict__ out_ipred,
    float* __restrict__ img_sum, float* __restrict__ img_cnt)
{
    __shared__ __align__(16) float sMem[4][32 * 36];   // per-wave H / logits

    int tid  = threadIdx.x;
    int wave = tid >> 6;
    int lane = tid & 63;
    int n31  = lane & 31;   // 32x32: A-row (m) / B-col (n) / D-col
    int kh   = lane >> 5;   // 32x32: k-half (k = kh*8 + j)
    int q    = lane >> 4;   // 16x16: quad 0..3
    int c16  = lane & 15;   // 16x16: A-row / D-col

    int base_w = blockIdx.x * 256 + wave * 64;

    // ---- EARLY: per-lane epilogue globals + zT gather (overlap with MLP) ----
    int n = base_w + lane;
    bool valid = (n < N_REFLNS);
    int nc = valid ? n : (N_REFLNS - 1);
    int m    = miller_id[nc];
    float io = iobs[nc];
    float sg = sigiobs[nc];
    int img  = image_id[nc];
    float f[MC];
    if (HAS_Z) {
        const float4* zp = (const float4*)(zT + (size_t)m * MC);
        float4 z0 = zp[0], z1 = zp[1];
        f[0] = z0.x; f[1] = z0.y; f[2] = z0.z; f[3] = z0.w;
        f[4] = z1.x; f[5] = z1.y; f[6] = z1.z; f[7] = z1.w;
    } else {
        float qlv = q_loc[m];
        float qsv = expf(q_log_scale[m]);
        #pragma unroll
        for (int s = 0; s < MC; s++) f[s] = qlv + qsv * eps[(size_t)s * N_RAC + m];
    }

    // ---- weight fragments ----
    bf16x8 W1h, W1l;   // B[k][n], k=kh*8+j, n=n31
    {
        float tmp[8];
        #pragma unroll
        for (int j = 0; j < 8; j++) tmp[j] = W1[(kh * 8 + j) * HIDDEN + n31];
        split_hilo(tmp, W1h, W1l);
    }
    float b1v = b1[n31];
    bf16x8 W2h, W2l;   // B[k][n], k=q*8+j, n=c16
    {
        float tmp[8];
        #pragma unroll
        for (int j = 0; j < 8; j++) tmp[j] = (c16 < MC) ? W2[(q * 8 + j) * MC + c16] : 0.0f;
        split_hilo(tmp, W2h, W2l);
    }
    float b2v = (c16 < MC) ? b2[c16] : 0.0f;

    float* Hb = &sMem[wave][0];
    f32x4 lgv[4];        // logits in C-layout regs, 4 tiles x 4 rows

    #pragma unroll
    for (int st = 0; st < 2; st++) {
        // ---- A-frag: meta[m][k], m=n31, k=kh*8+j (K=16 exact) ----
        int r = base_w + st * 32 + n31;
        if (r > N_REFLNS - 1) r = N_REFLNS - 1;
        const float4* mp = (const float4*)(metadata + (size_t)r * D_META + kh * 8);
        float4 a0 = mp[0], a1 = mp[1];
        float av[8] = {a0.x, a0.y, a0.z, a0.w, a1.x, a1.y, a1.z, a1.w};
        bf16x8 Ah, Al;
        split_hilo(av, Ah, Al);

        // ---- layer 1: one 32x32 tile, 3-term hi/lo ----
        f32x16 cc;
        #pragma unroll
        for (int i = 0; i < 16; i++) cc[i] = b1v;
        cc = MFMA32(Al, W1h, cc);
        cc = MFMA32(Ah, W1l, cc);
        cc = MFMA32(Ah, W1h, cc);
        #pragma unroll
        for (int i = 0; i < 16; i++) {
            int row = (i & 3) + 8 * (i >> 2) + 4 * kh;
            Hb[row * 36 + n31] = fmaxf(cc[i], 0.0f);
        }

        // ---- layer 2: two 16-row tiles; results stay in registers ----
        #pragma unroll
        for (int t2 = 0; t2 < 2; t2++) {
            const float4* hp = (const float4*)(Hb + (t2 * 16 + c16) * 36 + q * 8);
            bf16x8 Hh = pack8_rne(hp[0], hp[1]);
            f32x4 c2 = {b2v, b2v, b2v, b2v};
            c2 = MFMA16(Hh, W2l, c2);
            c2 = MFMA16(Hh, W2h, c2);
            lgv[st * 2 + t2] = c2;
        }
    }

    // ---- logits -> LDS (reusing Hb; same-wave DS ordering, no barrier) ----
    if (c16 < MC) {
        #pragma unroll
        for (int t = 0; t < 4; t++) {
            #pragma unroll
            for (int rr = 0; rr < 4; rr++) {
                Hb[t * 160 + (q * 4 + rr) * 10 + c16] = lgv[t][rr];
            }
        }
    }

    // ---- epilogue: one reflection per lane ----
    float ll_sum;
    {
        float lg[MC];
        const float2* lp = (const float2*)(Hb + (lane >> 4) * 160 + c16 * 10);
        float2 p0 = lp[0], p1 = lp[1], p2 = lp[2], p3 = lp[3];
        lg[0] = p0.x; lg[1] = p0.y; lg[2] = p1.x; lg[3] = p1.y;
        lg[4] = p2.x; lg[5] = p2.y; lg[6] = p3.x; lg[7] = p3.y;

        float sum_ip = 0.0f, sum_d2 = 0.0f;
        #pragma unroll
        for (int s = 0; s < MC; s++) {
            float sc = softplus_fast(lg[s]);
            float ip = f[s] * f[s] * sc;
            sum_ip += ip;
            float d = ip - io;
            sum_d2 = fmaf(d, d, sum_d2);
        }
        float inv = __builtin_amdgcn_rcpf(sg);
        if (valid) out_ipred[n] = sum_ip * (1.0f / MC);
        ll_sum = -0.5f * sum_d2 * inv * inv
                 - (float)MC * (0.5f * LOG_2PI)
                 - (float)MC * (LN2 * __builtin_amdgcn_logf(sg));
    }

    // ---- wave-level segmented inclusive scan over sorted image ids ----
    float v = valid ? ll_sum : 0.0f;
    float c = valid ? 1.0f : 0.0f;
    int   id = img;
    #pragma unroll
    for (int d = 1; d < 64; d <<= 1) {
        float pv = __shfl_up(v, d, 64);
        float pc = __shfl_up(c, d, 64);
        int  pid = __shfl_up(id, d, 64);
        if (lane >= d && pid == id) { v += pv; c += pc; }
    }
    int nid = __shfl_down(id, 1, 64);
    bool tail = (lane == 63) || (nid != id);
    if (valid && tail && c > 0.0f) {
        atomicAdd(&img_sum[id], v);
        atomicAdd(&img_cnt[id], c);
    }
}

// ---------------- Kernel C: finalize scalars ----------------
__global__ __launch_bounds__(256) void k_final(
    const float* __restrict__ img_sum,
    const float* __restrict__ img_cnt,
    const float* __restrict__ kl_sum,
    float* __restrict__ out)
{
    __shared__ float sred[256];
    float acc = 0.0f;
    for (int i = threadIdx.x; i < N_IMAGES; i += 256) {
        acc += img_sum[i] / fmaxf(img_cnt[i], 1.0f);
    }
    sred[threadIdx.x] = acc;
    __syncthreads();
    #pragma unroll
    for (int s = 128; s > 0; s >>= 1) {
        if (threadIdx.x < s) sred[threadIdx.x] += sred[threadIdx.x + s];
        __syncthreads();
    }
    if (threadIdx.x == 0) {
        float mean_ll = sred[0] / ((float)MC * (float)N_IMAGES);
        out[N_REFLNS]     = -mean_ll;
        out[N_REFLNS + 1] = kl_sum[0] * (1.0f / (float)N_RAC);
    }
}

extern "C" void kernel_launch(void* const* d_in, const int* in_sizes, int n_in,
                              void* d_out, int out_size, void* d_ws, size_t ws_size,
                              hipStream_t stream) {
    const float* q_loc       = (const float*)d_in[0];
    const float* q_log_scale = (const float*)d_in[1];
    const float* eps         = (const float*)d_in[2];
    const float* metadata    = (const float*)d_in[3];
    const float* W1          = (const float*)d_in[4];
    const float* b1          = (const float*)d_in[5];
    const float* W2          = (const float*)d_in[6];
    const float* b2          = (const float*)d_in[7];
    const float* iobs        = (const float*)d_in[8];
    const float* sigiobs     = (const float*)d_in[9];
    const int*   image_id    = (const int*)d_in[10];
    const int*   miller_id   = (const int*)d_in[11];
    float* out = (float*)d_out;

    char* ws = (char*)d_ws;
    float* img_sum = (float*)ws;                 // 8192
    float* img_cnt = img_sum + N_IMAGES;         // 8192
    float* kl_sum  = img_cnt + N_IMAGES;         // 1
    const size_t z_off = 65664;
    bool has_z = (ws_size >= z_off + (size_t)N_RAC * MC * sizeof(float));
    float* zT = has_z ? (float*)(ws + z_off) : nullptr;

    hipMemsetAsync(d_ws, 0, (2 * N_IMAGES + 1) * sizeof(float), stream);

    k_z_kl<<<(N_RAC / 4 + 255) / 256, 256, 0, stream>>>(q_loc, q_log_scale, eps, zT, kl_sum);

    if (has_z) {
        k_main<true><<<(N_REFLNS + 255) / 256, 256, 0, stream>>>(
            metadata, W1, b1, W2, b2, iobs, sigiobs, image_id, miller_id,
            zT, q_loc, q_log_scale, eps, out, img_sum, img_cnt);
    } else {
        k_main<false><<<(N_REFLNS + 255) / 256, 256, 0, stream>>>(
            metadata, W1, b1, W2, b2, iobs, sigiobs, image_id, miller_id,
            nullptr, q_loc, q_log_scale, eps, out, img_sum, img_cnt);
    }

    k_final<<<1, 256, 0, stream>>>(img_sum, img_cnt, kl_sum, out);
}